// Round 3
// baseline (470.193 us; speedup 1.0000x reference)
//
#include <hip/hip_runtime.h>

// FastGuidedFilter: 24 planes (8x3) of 1024x1024 f32, r=8 (17x17 clipped box).
//
// Two barrier-free sweep kernels through d_ws (A,b planes, 201 MB):
//  Each 64-lane wave owns 48 output columns (loads 64 = 48 + 2*8 halo) and
//  sweeps rows. Horizontal 17-tap window = log-tree shuffle sum (no LDS).
//  Vertical 17-tap window = 17-deep register ring (static indexing via a
//  fully unrolled 17-step inner loop). A,b (K1) / output (K2) emitted as the
//  window closes. No __syncthreads, no LDS arrays.
//
// Fallback: if ws_size < 201 MB, run the round-1 fused single kernel.

#define HH 1024
#define WW 1024
#define NPLANES 24
#define RAD 8
#define CH 128           // output rows per block chunk
#define NIT 9            // ceil((CH + 2*RAD) / 17)
#define WCOLS 48         // valid output cols per wave
#define BCOLS 192        // 4 waves per block
#define GX 6             // ceil(WW / BCOLS)
#define GY (HH / CH)     // 8

// 17-wide horizontal window sum centered on this lane's column.
// Valid only for lanes 8..55 (needs lanes l-8..l+8).
__device__ __forceinline__ float win17(float v) {
    float t = v + __shfl_down(v, 1, 64);
    t += __shfl_down(t, 2, 64);
    t += __shfl_down(t, 4, 64);
    t += __shfl_down(t, 8, 64);                       // sum v[l .. l+15]
    return __shfl_up(t, 8, 64) + __shfl_down(v, 8, 64); // sum v[l-8 .. l+8]
}

__global__ __launch_bounds__(256)
void fgf_ab(const float* __restrict__ x, const float* __restrict__ y,
            float* __restrict__ Aw, float* __restrict__ bw)
{
    const int lane = threadIdx.x & 63;
    const int wave = threadIdx.x >> 6;
    const int p  = blockIdx.z;
    const int R0 = blockIdx.y * CH;
    const int C0w = blockIdx.x * BCOLS + wave * WCOLS;
    const int gj = C0w - RAD + lane;               // column this lane handles
    const bool jload = (unsigned)gj < WW;
    const bool jout  = (lane >= RAD) && (lane < 64 - RAD) && jload;

    const size_t po = (size_t)p * HH * WW;
    const float* xp = x + po;
    const float* yp = y + po;
    float* Ap = Aw + po;
    float* bp = bw + po;

    float invCC = 1.f;
    if (jload) {
        int c = min(gj + RAD, WW - 1) - max(gj - RAD, 0) + 1;
        invCC = 1.0f / (float)c;
    }

    float sx = 0.f, sy = 0.f, sxy = 0.f, sxx = 0.f;   // running vertical sums
    float qx[17], qy[17], qxy[17], qxx[17];           // 17-deep rings (VGPRs)
    #pragma unroll
    for (int k = 0; k < 17; ++k) { qx[k]=0.f; qy[k]=0.f; qxy[k]=0.f; qxx[k]=0.f; }

    int r = R0 - RAD;                 // current input row
    const int rEnd = R0 + CH + RAD;   // rows >= rEnd are dummy (tail of unroll)
    for (int it = 0; it < NIT; ++it) {
        #pragma unroll
        for (int s = 0; s < 17; ++s) {
            float vx = 0.f, vy = 0.f;
            if ((unsigned)r < (unsigned)HH && r < rEnd && jload) {
                size_t g = (size_t)r * WW + gj;
                vx = xp[g]; vy = yp[g];
            }
            float hx  = win17(vx);
            float hy  = win17(vy);
            float hxy = win17(vx * vy);
            float hxx = win17(vx * vx);
            sx  += hx  - qx[s];  qx[s]  = hx;
            sy  += hy  - qy[s];  qy[s]  = hy;
            sxy += hxy - qxy[s]; qxy[s] = hxy;
            sxx += hxx - qxx[s]; qxx[s] = hxx;
            const int i = r - RAD;    // output row whose window just closed
            if (i >= R0 && i < R0 + CH && jout) {
                float cR = (float)(min(i + RAD, HH - 1) - max(i - RAD, 0) + 1);
                float invN = invCC * (1.0f / cR);
                float mx = sx * invN, my = sy * invN;
                float cov = sxy * invN - mx * my;
                float vr  = sxx * invN - mx * mx;
                float A = cov / (vr + 1e-8f);
                float b = my - A * mx;
                size_t g = (size_t)i * WW + gj;
                Ap[g] = A; bp[g] = b;
            }
            ++r;
        }
    }
}

__global__ __launch_bounds__(256)
void fgf_out(const float* __restrict__ Aw, const float* __restrict__ bw,
             const float* __restrict__ x, float* __restrict__ out)
{
    const int lane = threadIdx.x & 63;
    const int wave = threadIdx.x >> 6;
    const int p  = blockIdx.z;
    const int R0 = blockIdx.y * CH;
    const int C0w = blockIdx.x * BCOLS + wave * WCOLS;
    const int gj = C0w - RAD + lane;
    const bool jload = (unsigned)gj < WW;
    const bool jout  = (lane >= RAD) && (lane < 64 - RAD) && jload;

    const size_t po = (size_t)p * HH * WW;
    const float* Apl = Aw + po;
    const float* bpl = bw + po;
    const float* xp  = x + po;
    float* op = out + po;

    float invCC = 1.f;
    if (jload) {
        int c = min(gj + RAD, WW - 1) - max(gj - RAD, 0) + 1;
        invCC = 1.0f / (float)c;
    }

    float sA = 0.f, sB = 0.f;
    float qa[17], qb[17];
    #pragma unroll
    for (int k = 0; k < 17; ++k) { qa[k]=0.f; qb[k]=0.f; }

    int r = R0 - RAD;
    const int rEnd = R0 + CH + RAD;
    for (int it = 0; it < NIT; ++it) {
        #pragma unroll
        for (int s = 0; s < 17; ++s) {
            float vA = 0.f, vB = 0.f;
            if ((unsigned)r < (unsigned)HH && r < rEnd && jload) {
                size_t g = (size_t)r * WW + gj;
                vA = Apl[g]; vB = bpl[g];
            }
            float hA = win17(vA);
            float hB = win17(vB);
            sA += hA - qa[s]; qa[s] = hA;
            sB += hB - qb[s]; qb[s] = hB;
            const int i = r - RAD;
            if (i >= R0 && i < R0 + CH && jout) {
                float cR = (float)(min(i + RAD, HH - 1) - max(i - RAD, 0) + 1);
                float invN = invCC * (1.0f / cR);
                size_t g = (size_t)i * WW + gj;
                float xv = xp[g];
                op[g] = (sA * invN) * xv + (sB * invN);
            }
            ++r;
        }
    }
}

// ---------------- fallback: round-1 fused kernel (if ws too small) ----------------
#define TH 32
#define TW 64
#define RAWROWS (TH + 32)
#define RAWCOLS (TW + 32)
#define RAWSTR  (RAWCOLS + 1)
#define HROWS RAWROWS
#define HCOLS (TW + 16)
#define FHSTR  (HCOLS + 1)
#define BROWS (TH + 16)
#define STR2  (TW + 1)
#define REGA 15552
#define REGB 20736
#define SMEM_FLOATS (REGA + REGB)
#define SMEM_BYTES  (SMEM_FLOATS * 4)

extern "C" __global__ __launch_bounds__(256)
void fgf_fused(const float* __restrict__ x, const float* __restrict__ y,
               float* __restrict__ out)
{
    extern __shared__ float smem[];
    float* RA = smem;
    float* RB = smem + REGA;

    const int tid = threadIdx.x;
    const int tc = blockIdx.x;
    const int tr = blockIdx.y;
    const int p  = blockIdx.z;
    const int R0 = tr * TH;
    const int C0 = tc * TW;
    const size_t planeOff = (size_t)p * HH * WW;
    const float* xp = x + planeOff;
    const float* yp = y + planeOff;
    float* op = out + planeOff;

    float* rawx = RA;
    float* rawy = RA + RAWROWS * RAWSTR;

    for (int idx = tid; idx < RAWROWS * RAWCOLS; idx += 256) {
        int rr = idx / RAWCOLS;
        int cc = idx - rr * RAWCOLS;
        int gi = R0 - 16 + rr;
        int gj = C0 - 16 + cc;
        float vx = 0.f, vy = 0.f;
        if (gi >= 0 && gi < HH && gj >= 0 && gj < WW) {
            size_t g = (size_t)gi * WW + gj;
            vx = xp[g]; vy = yp[g];
        }
        rawx[rr * RAWSTR + cc] = vx;
        rawy[rr * RAWSTR + cc] = vy;
    }
    __syncthreads();

    {
        const int q   = tid >> 6;
        const int row = tid & 63;
        const float* rx = rawx + row * RAWSTR;
        const float* ry = rawy + row * RAWSTR;
        float* hq = RB + (q * HROWS + row) * FHSTR;
#define H1_SCAN(VAL_EXPR)                                    \
        {                                                    \
            float s = 0.f;                                   \
            for (int k = 0; k < 16; ++k) { int c = k; s += (VAL_EXPR); } \
            for (int j = 0; j < HCOLS; ++j) {                \
                { int c = j + 16; s += (VAL_EXPR); }         \
                hq[j] = s;                                   \
                { int c = j; s -= (VAL_EXPR); }              \
            }                                                \
        }
        if (q == 0)      H1_SCAN(rx[c])
        else if (q == 1) H1_SCAN(ry[c])
        else if (q == 2) H1_SCAN(rx[c] * ry[c])
        else             H1_SCAN(rx[c] * rx[c])
#undef H1_SCAN
    }
    __syncthreads();

    for (int item = tid; item < 4 * HCOLS; item += 256) {
        int q   = item / HCOLS;
        int col = item - q * HCOLS;
        const float* hq = RB + q * HROWS * FHSTR + col;
        float* bq = RA + q * BROWS * FHSTR + col;
        float s = 0.f;
        for (int k = 0; k < 16; ++k) s += hq[k * FHSTR];
        for (int i = 0; i < BROWS; ++i) {
            s += hq[(i + 16) * FHSTR];
            bq[i * FHSTR] = s;
            s -= hq[i * FHSTR];
        }
    }
    __syncthreads();

    for (int it = tid; it < BROWS * HCOLS; it += 256) {
        int ii = it / HCOLS;
        int jj = it - ii * HCOLS;
        int gi = R0 - 8 + ii;
        int gj = C0 - 8 + jj;
        float Av = 0.f, bv = 0.f;
        if (gi >= 0 && gi < HH && gj >= 0 && gj < WW) {
            float cntR = (float)(min(gi + RAD, HH - 1) - max(gi - RAD, 0) + 1);
            float cntC = (float)(min(gj + RAD, WW - 1) - max(gj - RAD, 0) + 1);
            float invN = 1.f / (cntR * cntC);
            float sxv  = RA[0 * BROWS * FHSTR + ii * FHSTR + jj];
            float syv  = RA[1 * BROWS * FHSTR + ii * FHSTR + jj];
            float sxyv = RA[2 * BROWS * FHSTR + ii * FHSTR + jj];
            float sxxv = RA[3 * BROWS * FHSTR + ii * FHSTR + jj];
            float mx  = sxv * invN;
            float my  = syv * invN;
            float cov = sxyv * invN - mx * my;
            float vr  = sxxv * invN - mx * mx;
            Av = cov / (vr + 1e-8f);
            bv = my - Av * mx;
        }
        RB[ii * FHSTR + jj] = Av;
        RB[BROWS * FHSTR + ii * FHSTR + jj] = bv;
    }
    __syncthreads();

    if (tid < 2 * BROWS) {
        int q   = tid / BROWS;
        int row = tid - q * BROWS;
        const float* src = RB + q * BROWS * FHSTR + row * FHSTR;
        float* dst = RA + (q * BROWS + row) * STR2;
        float s = 0.f;
        for (int k = 0; k < 16; ++k) s += src[k];
        for (int j = 0; j < TW; ++j) {
            s += src[j + 16];
            dst[j] = s;
            s -= src[j];
        }
    }
    __syncthreads();

    if (tid < 2 * TW) {
        int q   = tid >> 6;
        int col = tid & 63;
        const float* src = RA + q * BROWS * STR2 + col;
        float* dst = RB + q * TH * STR2 + col;
        float s = 0.f;
        for (int k = 0; k < 16; ++k) s += src[k * STR2];
        for (int i = 0; i < TH; ++i) {
            s += src[(i + 16) * STR2];
            dst[i * STR2] = s;
            s -= src[i * STR2];
        }
    }
    __syncthreads();

    for (int it = tid; it < TH * TW; it += 256) {
        int ii = it >> 6;
        int jj = it & 63;
        int gi = R0 + ii;
        int gj = C0 + jj;
        float cntR = (float)(min(gi + RAD, HH - 1) - max(gi - RAD, 0) + 1);
        float cntC = (float)(min(gj + RAD, WW - 1) - max(gj - RAD, 0) + 1);
        float invN = 1.f / (cntR * cntC);
        float mA = RB[ii * STR2 + jj] * invN;
        float mb = RB[TH * STR2 + ii * STR2 + jj] * invN;
        size_t g = (size_t)gi * WW + gj;
        op[g] = mA * xp[g] + mb;
    }
}

extern "C" void kernel_launch(void* const* d_in, const int* in_sizes, int n_in,
                              void* d_out, int out_size, void* d_ws, size_t ws_size,
                              hipStream_t stream) {
    const float* x = (const float*)d_in[0];
    const float* y = (const float*)d_in[1];
    float* out = (float*)d_out;

    const size_t planeFloats = (size_t)NPLANES * HH * WW;   // 24M
    const size_t wsNeed = 2 * planeFloats * sizeof(float);  // 201.3 MB

    if (ws_size >= wsNeed) {
        float* Aw = (float*)d_ws;
        float* bw = Aw + planeFloats;
        dim3 grid(GX, GY, NPLANES);
        fgf_ab<<<grid, 256, 0, stream>>>(x, y, Aw, bw);
        fgf_out<<<grid, 256, 0, stream>>>(Aw, bw, x, out);
    } else {
        hipFuncSetAttribute((const void*)fgf_fused,
                            hipFuncAttributeMaxDynamicSharedMemorySize, SMEM_BYTES);
        dim3 grid(WW / TW, HH / TH, NPLANES);
        fgf_fused<<<grid, 256, SMEM_BYTES, stream>>>(x, y, out);
    }
}

// Round 4
// 277.465 us; speedup vs baseline: 1.6946x; 1.6946x over previous
//
#include <hip/hip_runtime.h>

// FastGuidedFilter: 24 planes (8x3) of 1024x1024 f32, r=8 (17x17 clipped box).
//
// Two barrier-free full-row sweep kernels through d_ws (A,b planes, 201 MB).
// Each 64-lane wave owns a FULL 1024-col row (16 contiguous cols/lane) and
// sweeps CH=16 output rows. Horizontal 17-tap window via row cumsum:
//   local prefix (15 adds) + 6-step wave scan + ~17 shuffles per 16 outputs,
//   window = C[j+8] - C[j-9] with image-edge clamps.
// Vertical 17-tap window via running sum; the trailing row (r-17) is
// re-loaded (L2/L3-warm) and its horizontal window recomputed, avoiding a
// 17-deep x 4-quantity x 16-col register ring. No LDS arrays, no barriers.
//
// Fallback: if ws_size < 201 MB, run the round-1 fused single kernel.

#define HH 1024
#define WW 1024
#define NPLANES 24
#define RAD 8
#define CH 16              // output rows per wave
#define NJOBS (NPLANES * (HH / CH))   // 1536 single-wave blocks

// Horizontal 17-wide clipped window sums for 16 cols/lane (lane owns cols
// 16*lane .. 16*lane+15; wave covers the full 1024-col row).
// w[m] = sum_{k=max(0,j-8)}^{min(1023,j+8)} q_row[k],  j = 16*lane+m.
__device__ __forceinline__ void hwin17(const float* __restrict__ q,
                                       float* __restrict__ w, int lane) {
    float P[16];
    P[0] = q[0];
#pragma unroll
    for (int m = 1; m < 16; ++m) P[m] = P[m - 1] + q[m];
    float t = P[15];
#pragma unroll
    for (int d = 1; d < 64; d <<= 1) {
        float u = __shfl_up(t, d, 64);
        if (lane >= d) t += u;
    }
    const float B = t - P[15];          // exclusive cumsum base of this lane
    float C[16];
#pragma unroll
    for (int m = 0; m < 16; ++m) C[m] = B + P[m];   // inclusive global cumsum
    const float Ctot = C[15];           // lane 63: total row sum (right clamp)
    // m = 0..7: lead = own C[m+8]; trail = lane-1's C[m+7] (0 at left edge)
#pragma unroll
    for (int m = 0; m < 8; ++m) {
        float tr = __shfl_up(C[m + 7], 1, 64);
        if (lane == 0) tr = 0.f;
        w[m] = C[m + 8] - tr;
    }
    // m = 8: lead = lane+1's C[0] (clamp to total at right edge);
    //        trail = lane-1's C[15] (0 at left edge)
    {
        float ld = __shfl_down(C[0], 1, 64);
        if (lane == 63) ld = Ctot;
        float tr = __shfl_up(C[15], 1, 64);
        if (lane == 0) tr = 0.f;
        w[8] = ld - tr;
    }
    // m = 9..15: lead = lane+1's C[m-8] (clamp); trail = own C[m-9]
#pragma unroll
    for (int m = 9; m < 16; ++m) {
        float ld = __shfl_down(C[m - 8], 1, 64);
        if (lane == 63) ld = Ctot;
        w[m] = ld - C[m - 9];
    }
}

__device__ __forceinline__ void load16(const float* __restrict__ rowp, int lane,
                                       float* __restrict__ d) {
    const float4* p = (const float4*)rowp;
#pragma unroll
    for (int k = 0; k < 4; ++k) {
        float4 a = p[lane * 4 + k];
        d[k * 4 + 0] = a.x; d[k * 4 + 1] = a.y;
        d[k * 4 + 2] = a.z; d[k * 4 + 3] = a.w;
    }
}

__global__ __launch_bounds__(64)
void fgf_ab(const float* __restrict__ x, const float* __restrict__ y,
            float* __restrict__ Aw, float* __restrict__ bw)
{
    const int lane = threadIdx.x;
    const int job  = blockIdx.x;
    const int p    = job / (HH / CH);
    const int R0   = (job - p * (HH / CH)) * CH;
    const size_t po = (size_t)p * HH * WW;
    const float* xp = x + po;
    const float* yp = y + po;
    float* Ap = Aw + po;
    float* bp = bw + po;

    float invCC[16];
#pragma unroll
    for (int m = 0; m < 16; ++m) {
        int j = lane * 16 + m;
        int c = min(j + RAD, WW - 1) - max(j - RAD, 0) + 1;
        invCC[m] = 1.f / (float)c;
    }

    float sx[16], sy[16], sxy[16], sxx[16];
#pragma unroll
    for (int m = 0; m < 16; ++m) { sx[m] = 0.f; sy[m] = 0.f; sxy[m] = 0.f; sxx[m] = 0.f; }

    for (int r = R0 - RAD; r <= R0 + CH - 1 + RAD; ++r) {
        const int rt = r - (2 * RAD + 1);
        const bool doLead  = (r >= 0) && (r < HH);
        const bool doTrail = (rt >= R0 - RAD) && (rt >= 0);

        float xv[16], yv[16], xt[16], yt[16];
        if (doLead) {
            load16(xp + (size_t)r * WW, lane, xv);
            load16(yp + (size_t)r * WW, lane, yv);
        }
        if (doTrail) {
            load16(xp + (size_t)rt * WW, lane, xt);
            load16(yp + (size_t)rt * WW, lane, yt);
        }

        if (doLead) {
            float t[16], w[16];
            hwin17(xv, w, lane);
#pragma unroll
            for (int m = 0; m < 16; ++m) sx[m] += w[m];
            hwin17(yv, w, lane);
#pragma unroll
            for (int m = 0; m < 16; ++m) sy[m] += w[m];
#pragma unroll
            for (int m = 0; m < 16; ++m) t[m] = xv[m] * yv[m];
            hwin17(t, w, lane);
#pragma unroll
            for (int m = 0; m < 16; ++m) sxy[m] += w[m];
#pragma unroll
            for (int m = 0; m < 16; ++m) t[m] = xv[m] * xv[m];
            hwin17(t, w, lane);
#pragma unroll
            for (int m = 0; m < 16; ++m) sxx[m] += w[m];
        }
        if (doTrail) {
            float t[16], w[16];
            hwin17(xt, w, lane);
#pragma unroll
            for (int m = 0; m < 16; ++m) sx[m] -= w[m];
            hwin17(yt, w, lane);
#pragma unroll
            for (int m = 0; m < 16; ++m) sy[m] -= w[m];
#pragma unroll
            for (int m = 0; m < 16; ++m) t[m] = xt[m] * yt[m];
            hwin17(t, w, lane);
#pragma unroll
            for (int m = 0; m < 16; ++m) sxy[m] -= w[m];
#pragma unroll
            for (int m = 0; m < 16; ++m) t[m] = xt[m] * xt[m];
            hwin17(t, w, lane);
#pragma unroll
            for (int m = 0; m < 16; ++m) sxx[m] -= w[m];
        }

        const int i = r - RAD;
        if (i >= R0) {
            float cR = (float)(min(i + RAD, HH - 1) - max(i - RAD, 0) + 1);
            float invCR = 1.f / cR;
            float Ao[16], Bo[16];
#pragma unroll
            for (int m = 0; m < 16; ++m) {
                float invN = invCR * invCC[m];
                float mx = sx[m] * invN, my = sy[m] * invN;
                float cov = sxy[m] * invN - mx * my;
                float vr  = sxx[m] * invN - mx * mx;
                float A = cov / (vr + 1e-8f);
                Ao[m] = A;
                Bo[m] = my - A * mx;
            }
            float4* Arow = (float4*)(Ap + (size_t)i * WW);
            float4* Brow = (float4*)(bp + (size_t)i * WW);
#pragma unroll
            for (int k = 0; k < 4; ++k) {
                Arow[lane * 4 + k] = make_float4(Ao[k*4+0], Ao[k*4+1], Ao[k*4+2], Ao[k*4+3]);
                Brow[lane * 4 + k] = make_float4(Bo[k*4+0], Bo[k*4+1], Bo[k*4+2], Bo[k*4+3]);
            }
        }
    }
}

__global__ __launch_bounds__(64)
void fgf_out(const float* __restrict__ Aw, const float* __restrict__ bw,
             const float* __restrict__ x, float* __restrict__ out)
{
    const int lane = threadIdx.x;
    const int job  = blockIdx.x;
    const int p    = job / (HH / CH);
    const int R0   = (job - p * (HH / CH)) * CH;
    const size_t po = (size_t)p * HH * WW;
    const float* Apl = Aw + po;
    const float* bpl = bw + po;
    const float* xp  = x + po;
    float* op = out + po;

    float invCC[16];
#pragma unroll
    for (int m = 0; m < 16; ++m) {
        int j = lane * 16 + m;
        int c = min(j + RAD, WW - 1) - max(j - RAD, 0) + 1;
        invCC[m] = 1.f / (float)c;
    }

    float sA[16], sB[16];
#pragma unroll
    for (int m = 0; m < 16; ++m) { sA[m] = 0.f; sB[m] = 0.f; }

    for (int r = R0 - RAD; r <= R0 + CH - 1 + RAD; ++r) {
        const int rt = r - (2 * RAD + 1);
        const bool doLead  = (r >= 0) && (r < HH);
        const bool doTrail = (rt >= R0 - RAD) && (rt >= 0);

        float av[16], bv[16], at[16], bt[16];
        if (doLead) {
            load16(Apl + (size_t)r * WW, lane, av);
            load16(bpl + (size_t)r * WW, lane, bv);
        }
        if (doTrail) {
            load16(Apl + (size_t)rt * WW, lane, at);
            load16(bpl + (size_t)rt * WW, lane, bt);
        }

        if (doLead) {
            float w[16];
            hwin17(av, w, lane);
#pragma unroll
            for (int m = 0; m < 16; ++m) sA[m] += w[m];
            hwin17(bv, w, lane);
#pragma unroll
            for (int m = 0; m < 16; ++m) sB[m] += w[m];
        }
        if (doTrail) {
            float w[16];
            hwin17(at, w, lane);
#pragma unroll
            for (int m = 0; m < 16; ++m) sA[m] -= w[m];
            hwin17(bt, w, lane);
#pragma unroll
            for (int m = 0; m < 16; ++m) sB[m] -= w[m];
        }

        const int i = r - RAD;
        if (i >= R0) {
            float cR = (float)(min(i + RAD, HH - 1) - max(i - RAD, 0) + 1);
            float invCR = 1.f / cR;
            float xv[16];
            load16(xp + (size_t)i * WW, lane, xv);
            float Oo[16];
#pragma unroll
            for (int m = 0; m < 16; ++m) {
                float invN = invCR * invCC[m];
                Oo[m] = (sA[m] * invN) * xv[m] + sB[m] * invN;
            }
            float4* Orow = (float4*)(op + (size_t)i * WW);
#pragma unroll
            for (int k = 0; k < 4; ++k)
                Orow[lane * 4 + k] = make_float4(Oo[k*4+0], Oo[k*4+1], Oo[k*4+2], Oo[k*4+3]);
        }
    }
}

// ---------------- fallback: round-1 fused kernel (if ws too small) ----------------
#define TH 32
#define TW 64
#define RAWROWS (TH + 32)
#define RAWCOLS (TW + 32)
#define RAWSTR  (RAWCOLS + 1)
#define HROWS RAWROWS
#define HCOLS (TW + 16)
#define FHSTR  (HCOLS + 1)
#define BROWS (TH + 16)
#define STR2  (TW + 1)
#define REGA 15552
#define REGB 20736
#define SMEM_FLOATS (REGA + REGB)
#define SMEM_BYTES  (SMEM_FLOATS * 4)

extern "C" __global__ __launch_bounds__(256)
void fgf_fused(const float* __restrict__ x, const float* __restrict__ y,
               float* __restrict__ out)
{
    extern __shared__ float smem[];
    float* RA = smem;
    float* RB = smem + REGA;

    const int tid = threadIdx.x;
    const int tc = blockIdx.x;
    const int tr = blockIdx.y;
    const int p  = blockIdx.z;
    const int R0 = tr * TH;
    const int C0 = tc * TW;
    const size_t planeOff = (size_t)p * HH * WW;
    const float* xp = x + planeOff;
    const float* yp = y + planeOff;
    float* op = out + planeOff;

    float* rawx = RA;
    float* rawy = RA + RAWROWS * RAWSTR;

    for (int idx = tid; idx < RAWROWS * RAWCOLS; idx += 256) {
        int rr = idx / RAWCOLS;
        int cc = idx - rr * RAWCOLS;
        int gi = R0 - 16 + rr;
        int gj = C0 - 16 + cc;
        float vx = 0.f, vy = 0.f;
        if (gi >= 0 && gi < HH && gj >= 0 && gj < WW) {
            size_t g = (size_t)gi * WW + gj;
            vx = xp[g]; vy = yp[g];
        }
        rawx[rr * RAWSTR + cc] = vx;
        rawy[rr * RAWSTR + cc] = vy;
    }
    __syncthreads();

    {
        const int q   = tid >> 6;
        const int row = tid & 63;
        const float* rx = rawx + row * RAWSTR;
        const float* ry = rawy + row * RAWSTR;
        float* hq = RB + (q * HROWS + row) * FHSTR;
#define H1_SCAN(VAL_EXPR)                                    \
        {                                                    \
            float s = 0.f;                                   \
            for (int k = 0; k < 16; ++k) { int c = k; s += (VAL_EXPR); } \
            for (int j = 0; j < HCOLS; ++j) {                \
                { int c = j + 16; s += (VAL_EXPR); }         \
                hq[j] = s;                                   \
                { int c = j; s -= (VAL_EXPR); }              \
            }                                                \
        }
        if (q == 0)      H1_SCAN(rx[c])
        else if (q == 1) H1_SCAN(ry[c])
        else if (q == 2) H1_SCAN(rx[c] * ry[c])
        else             H1_SCAN(rx[c] * rx[c])
#undef H1_SCAN
    }
    __syncthreads();

    for (int item = tid; item < 4 * HCOLS; item += 256) {
        int q   = item / HCOLS;
        int col = item - q * HCOLS;
        const float* hq = RB + q * HROWS * FHSTR + col;
        float* bq = RA + q * BROWS * FHSTR + col;
        float s = 0.f;
        for (int k = 0; k < 16; ++k) s += hq[k * FHSTR];
        for (int i = 0; i < BROWS; ++i) {
            s += hq[(i + 16) * FHSTR];
            bq[i * FHSTR] = s;
            s -= hq[i * FHSTR];
        }
    }
    __syncthreads();

    for (int it = tid; it < BROWS * HCOLS; it += 256) {
        int ii = it / HCOLS;
        int jj = it - ii * HCOLS;
        int gi = R0 - 8 + ii;
        int gj = C0 - 8 + jj;
        float Av = 0.f, bv = 0.f;
        if (gi >= 0 && gi < HH && gj >= 0 && gj < WW) {
            float cntR = (float)(min(gi + RAD, HH - 1) - max(gi - RAD, 0) + 1);
            float cntC = (float)(min(gj + RAD, WW - 1) - max(gj - RAD, 0) + 1);
            float invN = 1.f / (cntR * cntC);
            float sxv  = RA[0 * BROWS * FHSTR + ii * FHSTR + jj];
            float syv  = RA[1 * BROWS * FHSTR + ii * FHSTR + jj];
            float sxyv = RA[2 * BROWS * FHSTR + ii * FHSTR + jj];
            float sxxv = RA[3 * BROWS * FHSTR + ii * FHSTR + jj];
            float mx  = sxv * invN;
            float my  = syv * invN;
            float cov = sxyv * invN - mx * my;
            float vr  = sxxv * invN - mx * mx;
            Av = cov / (vr + 1e-8f);
            bv = my - Av * mx;
        }
        RB[ii * FHSTR + jj] = Av;
        RB[BROWS * FHSTR + ii * FHSTR + jj] = bv;
    }
    __syncthreads();

    if (tid < 2 * BROWS) {
        int q   = tid / BROWS;
        int row = tid - q * BROWS;
        const float* src = RB + q * BROWS * FHSTR + row * FHSTR;
        float* dst = RA + (q * BROWS + row) * STR2;
        float s = 0.f;
        for (int k = 0; k < 16; ++k) s += src[k];
        for (int j = 0; j < TW; ++j) {
            s += src[j + 16];
            dst[j] = s;
            s -= src[j];
        }
    }
    __syncthreads();

    if (tid < 2 * TW) {
        int q   = tid >> 6;
        int col = tid & 63;
        const float* src = RA + q * BROWS * STR2 + col;
        float* dst = RB + q * TH * STR2 + col;
        float s = 0.f;
        for (int k = 0; k < 16; ++k) s += src[k * STR2];
        for (int i = 0; i < TH; ++i) {
            s += src[(i + 16) * STR2];
            dst[i * STR2] = s;
            s -= src[i * STR2];
        }
    }
    __syncthreads();

    for (int it = tid; it < TH * TW; it += 256) {
        int ii = it >> 6;
        int jj = it & 63;
        int gi = R0 + ii;
        int gj = C0 + jj;
        float cntR = (float)(min(gi + RAD, HH - 1) - max(gi - RAD, 0) + 1);
        float cntC = (float)(min(gj + RAD, WW - 1) - max(gj - RAD, 0) + 1);
        float invN = 1.f / (cntR * cntC);
        float mA = RB[ii * STR2 + jj] * invN;
        float mb = RB[TH * STR2 + ii * STR2 + jj] * invN;
        size_t g = (size_t)gi * WW + gj;
        op[g] = mA * xp[g] + mb;
    }
}

extern "C" void kernel_launch(void* const* d_in, const int* in_sizes, int n_in,
                              void* d_out, int out_size, void* d_ws, size_t ws_size,
                              hipStream_t stream) {
    const float* x = (const float*)d_in[0];
    const float* y = (const float*)d_in[1];
    float* out = (float*)d_out;

    const size_t planeFloats = (size_t)NPLANES * HH * WW;   // 24M
    const size_t wsNeed = 2 * planeFloats * sizeof(float);  // 201.3 MB

    if (ws_size >= wsNeed) {
        float* Aw = (float*)d_ws;
        float* bw = Aw + planeFloats;
        fgf_ab<<<dim3(NJOBS), 64, 0, stream>>>(x, y, Aw, bw);
        fgf_out<<<dim3(NJOBS), 64, 0, stream>>>(Aw, bw, x, out);
    } else {
        hipFuncSetAttribute((const void*)fgf_fused,
                            hipFuncAttributeMaxDynamicSharedMemorySize, SMEM_BYTES);
        dim3 grid(WW / TW, HH / TH, NPLANES);
        fgf_fused<<<grid, 256, SMEM_BYTES, stream>>>(x, y, out);
    }
}